// Round 3
// baseline (1627.805 us; speedup 1.0000x reference)
//
#include <hip/hip_runtime.h>

// lstm_seq2seq fused persistent kernel for MI355X (gfx950), R3.
// 512 WGs x 32 rows (2 WG/CU -> MFMA phase of one WG overlaps VALU phase of
// the other). Gates = [h|x] @ Waug^T via mfma_f32_16x16x32_f16; bias in regs.
// Decoder feedback folded into weights: W_eff = W_hh_dec + W_ih_dec@W_out,
// b_eff = b_dec + W_ih_dec@b_out  =>  no xdec, no second barrier, decoder
// steps >0 use K=256 (8 k-tiles). Out-projection off critical path.
// Register budget @ launch_bounds(512,4): acc 64 (AGPR) + arch <=64.

#define SEQ  20
#define TLEN 30

typedef _Float16 half8   __attribute__((ext_vector_type(8)));
typedef float    floatx4 __attribute__((ext_vector_type(4)));

// Packed weights (rewritten every launch). Layout:
//   [(tile*9 + kt)*512 + q*128 + l16*8 + j],  n = 16*tile + l16, k = 32*kt+8*q+j
__device__ _Float16 g_whh_enc[1024 * 288];   // k>=256: folded W_ih_enc@W_emb cols
__device__ _Float16 g_whh_dec[1024 * 288];   // k>=256: W_ih_dec cols (dec step 0)
__device__ _Float16 g_whh_deff[1024 * 288];  // W_hh_dec + W_ih_dec@W_out; kt=8 zero
__device__ _Float16 g_wout[512];             // W_out [2][256] f16
__device__ float    g_bias[3 * 1024];        // 0: enc_aug, 1: b_dec, 2: b_eff

__global__ void prep_kernel(const float* __restrict__ W_emb,
                            const float* __restrict__ b_emb,
                            const float* __restrict__ W_ih_enc,
                            const float* __restrict__ W_hh_enc,
                            const float* __restrict__ b_enc,
                            const float* __restrict__ W_ih_dec,
                            const float* __restrict__ W_hh_dec,
                            const float* __restrict__ b_dec,
                            const float* __restrict__ W_out,
                            const float* __restrict__ b_out) {
    int gid = blockIdx.x * blockDim.x + threadIdx.x;
    int stride = gridDim.x * blockDim.x;
    for (int s = gid; s < 1024 * 288; s += stride) {
        int n = s / 288, k = s - n * 288;
        int tile = n >> 4, l16 = n & 15;
        int kt = k >> 5, q = (k >> 3) & 3, j = k & 7;
        int dst = (tile * 9 + kt) * 512 + q * 128 + l16 * 8 + j;
        float fe = 0.f, fd = 0.f, ff = 0.f;
        if (k < 256) {
            fe = W_hh_enc[n * 256 + k];
            fd = W_hh_dec[n * 256 + k];
            ff = fd + W_ih_dec[2 * n] * W_out[k] + W_ih_dec[2 * n + 1] * W_out[256 + k];
        } else {
            int kp = k - 256;
            if (kp < 2) {
                fd = W_ih_dec[2 * n + kp];
                const float* wr = &W_ih_enc[n * 64];
                for (int e = 0; e < 64; e++) fe = fmaf(wr[e], W_emb[2 * e + kp], fe);
            }
        }
        g_whh_enc[dst]  = (_Float16)fe;
        g_whh_dec[dst]  = (_Float16)fd;
        g_whh_deff[dst] = (_Float16)ff;
    }
    if (gid < 512) g_wout[gid] = (_Float16)W_out[gid];
    if (gid < 1024) {
        float ba = b_enc[gid];
        const float* wr = &W_ih_enc[gid * 64];
        for (int e = 0; e < 64; e++) ba = fmaf(wr[e], b_emb[e], ba);
        g_bias[gid] = ba;
        g_bias[1024 + gid] = b_dec[gid];
        g_bias[2048 + gid] = b_dec[gid] + W_ih_dec[2 * gid] * b_out[0]
                                        + W_ih_dec[2 * gid + 1] * b_out[1];
    }
}

__global__ __launch_bounds__(512, 4) void lstm_fused(
        const float* __restrict__ x_input,    // [20][16384][2]
        const float* __restrict__ b_out,      // [2]
        float* __restrict__ out)              // [30][16384][2]
{
    // h packed A-layout: [buf][mt(2)][kt(9)][512] halves; kt=8 holds x0,x1
    __shared__ __align__(16) _Float16 h_pack[2][9216];   // 36864 B
    __shared__ __align__(16) float    c_lds[8192];       // 32768 B
    __shared__ __align__(16) _Float16 wout_lds[512];     // 1024 B

    const int tid = threadIdx.x;
    const int w   = tid >> 6;       // wave 0..7, owns hidden cols [32w,32w+32)
    const int L   = tid & 63;
    const int l16 = L & 15;
    const int q   = L >> 4;
    const long row0 = (long)blockIdx.x * 32;

    // ---- init: zero h bufs + c, stage x(0) ----
    {
        int* hz = (int*)&h_pack[0][0];
        for (int idx = tid; idx < 9216; idx += 512) hz[idx] = 0;  // both bufs
        for (int idx = tid; idx < 8192; idx += 512) c_lds[idx] = 0.f;
        if (tid < 64) {
            int row = tid >> 1, jj = tid & 1;
            h_pack[0][((row >> 4) * 9 + 8) * 512 + (row & 15) * 8 + jj] =
                (_Float16)x_input[(row0 + row) * 2 + jj];
        }
        wout_lds[tid & 511] = g_wout[tid & 511];
    }

    const float bo = b_out[(L >> 3) & 1];
    const int aoff = q * 128 + l16 * 8;
    int b_off[8];                    // i = t2*4 + g
#pragma unroll
    for (int i = 0; i < 8; i++)
        b_off[i] = (16 * (i & 3) + 2 * w + (i >> 2)) * 4608 + aoff;

    // gate index for per-lane bias: n = 256g + 32w + 16t2 + l16
    float b_reg[8];
#pragma unroll
    for (int i = 0; i < 8; i++)
        b_reg[i] = g_bias[256 * (i & 3) + 32 * w + 16 * (i >> 2) + l16];

    floatx4 acc[2][8];   // [mt][i]; D: row=16mt+4q+r (batch), col=l16 (gate)

    __syncthreads();

    int cur = 0;
#pragma unroll 1
    for (int t = 0; t < SEQ + TLEN; t++) {
        const bool aug = (t <= SEQ);
        const _Float16* __restrict__ Wb =
            (t < SEQ) ? g_whh_enc : (t == SEQ) ? g_whh_dec : g_whh_deff;
        const _Float16* __restrict__ hp = h_pack[cur];
        _Float16* __restrict__ hn = h_pack[cur ^ 1];

        // phase-boundary bias reloads (uniform branches, twice per launch)
        if (t == SEQ) {
#pragma unroll
            for (int i = 0; i < 8; i++)
                b_reg[i] = g_bias[1024 + 256 * (i & 3) + 32 * w + 16 * (i >> 2) + l16];
        } else if (t == SEQ + 1) {
#pragma unroll
            for (int i = 0; i < 8; i++)
                b_reg[i] = g_bias[2048 + 256 * (i & 3) + 32 * w + 16 * (i >> 2) + l16];
        }

        // ---- gates = bias + [h|x] @ Waug^T ----
#pragma unroll
        for (int mt = 0; mt < 2; mt++)
#pragma unroll
            for (int i = 0; i < 8; i++) {
                floatx4 a; a[0] = b_reg[i]; a[1] = b_reg[i];
                a[2] = b_reg[i]; a[3] = b_reg[i];
                acc[mt][i] = a;
            }

#pragma unroll
        for (int kt = 0; kt < 9; kt++) {
            if (kt == 8 && !aug) continue;   // K=256 for folded decoder steps
            half8 A[2];
#pragma unroll
            for (int mt = 0; mt < 2; mt++)
                A[mt] = *(const half8*)&hp[(mt * 9 + kt) * 512 + aoff];
#pragma unroll
            for (int i = 0; i < 8; i++) {
                half8 B = *(const half8*)&Wb[b_off[i] + kt * 512];
#pragma unroll
                for (int mt = 0; mt < 2; mt++)
                    acc[mt][i] = __builtin_amdgcn_mfma_f32_16x16x32_f16(
                        A[mt], B, acc[mt][i], 0, 0, 0);
            }
        }

        // next-step x load (encoder + feed of x19 into dec step 0)
        float xval = 0.f;
        if (t < SEQ && tid < 64) {
            int src_t = (t + 1 < SEQ) ? t + 1 : SEQ - 1;
            xval = x_input[(long)src_t * 32768 + (row0 + (tid >> 1)) * 2 + (tid & 1)];
        }

        // ---- elementwise LSTM update; h(f16) -> nxt buffer ----
#pragma unroll
        for (int mt = 0; mt < 2; mt++)
#pragma unroll
            for (int t2 = 0; t2 < 2; t2++) {
                int ci = ((w * 4 + mt * 2 + t2) * 64 + L) * 4;
                floatx4 c4 = *(floatx4*)&c_lds[ci];
                _Float16* hw = &hn[(mt * 9 + w) * 512 +
                                   (2 * t2 + (l16 >> 3)) * 128 + (l16 & 7)];
#pragma unroll
                for (int r = 0; r < 4; r++) {
                    float ai = acc[mt][t2 * 4 + 0][r];
                    float af = acc[mt][t2 * 4 + 1][r];
                    float ag = fmaxf(acc[mt][t2 * 4 + 2][r], -30.f);
                    float ao = acc[mt][t2 * 4 + 3][r];
                    float eI = __expf(-ai);
                    float eG = __expf(-2.f * ag);
                    float eF = __expf(-af);
                    float ig = (1.f - eG) *
                        __builtin_amdgcn_rcpf((1.f + eI) * (1.f + eG));
                    float fs = __builtin_amdgcn_rcpf(1.f + eF);
                    float cn = fmaf(fs, c4[r], ig);
                    c4[r] = cn;
                    float cnc = fmaxf(cn, -30.f);
                    float eO = __expf(-ao);
                    float eC = __expf(-2.f * cnc);
                    float hv = (1.f - eC) *
                        __builtin_amdgcn_rcpf((1.f + eO) * (1.f + eC));
                    hw[(4 * q + r) * 8] = (_Float16)hv;
                }
                *(floatx4*)&c_lds[ci] = c4;
            }

        if (t < SEQ && tid < 64) {
            int row = tid >> 1, jj = tid & 1;
            hn[((row >> 4) * 9 + 8) * 512 + (row & 15) * 8 + jj] = (_Float16)xval;
        }

        __syncthreads();   // h complete

        // ---- out = h_new @ W_out^T + b_out (no feedback needed; no barrier) ----
        if (t >= SEQ) {
            int o = 8 * w + (L >> 3);          // 64 outputs, 8 lanes each
            int m = o >> 1, jj = o & 1;
            const _Float16* hb = &hn[((m >> 4) * 9 + (L & 7)) * 512 + (m & 15) * 8];
            const _Float16* wb = &wout_lds[jj * 256 + (L & 7) * 32];
            float s = 0.f;
#pragma unroll
            for (int qq = 0; qq < 4; qq++) {
                half8 hv = *(const half8*)&hb[qq * 128];
                half8 wv = *(const half8*)&wb[qq * 8];
#pragma unroll
                for (int u = 0; u < 8; u++)
                    s = fmaf((float)hv[u], (float)wv[u], s);
            }
            s += __shfl_xor(s, 1);
            s += __shfl_xor(s, 2);
            s += __shfl_xor(s, 4);
            if ((L & 7) == 0)
                out[(long)(t - SEQ) * 32768 + (row0 + m) * 2 + jj] = s + bo;
        }

        cur ^= 1;
    }
}

extern "C" void kernel_launch(void* const* d_in, const int* in_sizes, int n_in,
                              void* d_out, int out_size, void* d_ws, size_t ws_size,
                              hipStream_t stream) {
    (void)in_sizes; (void)n_in; (void)d_ws; (void)ws_size; (void)out_size;
    const float* x      = (const float*)d_in[0];
    const float* W_emb  = (const float*)d_in[1];
    const float* b_emb  = (const float*)d_in[2];
    const float* W_ih_e = (const float*)d_in[3];
    const float* W_hh_e = (const float*)d_in[4];
    const float* b_enc  = (const float*)d_in[5];
    const float* W_ih_d = (const float*)d_in[6];
    const float* W_hh_d = (const float*)d_in[7];
    const float* b_dec  = (const float*)d_in[8];
    const float* W_out  = (const float*)d_in[9];
    const float* b_out  = (const float*)d_in[10];
    float* outp = (float*)d_out;

    prep_kernel<<<512, 256, 0, stream>>>(W_emb, b_emb, W_ih_e, W_hh_e, b_enc,
                                         W_ih_d, W_hh_d, b_dec, W_out, b_out);
    lstm_fused<<<512, 512, 0, stream>>>(x, b_out, outp);
}

// Round 4
// 737.905 us; speedup vs baseline: 2.2060x; 2.2060x over previous
//
#include <hip/hip_runtime.h>

// lstm_seq2seq fused persistent kernel for MI355X (gfx950), R4.
// 512 WGs x 256 threads x 32 rows; launch_bounds(256,2) -> 256 VGPR budget AND
// 2 WG/CU (anti-phase MFMA/VALU overlap, no spills - R3's failure mode).
// MFMA orientation: A = weights (L2-streamed, wave-contiguous packing),
// B = h (LDS, double-buffered). D: col=batch, row=gate -> h writeback is
// packed ds_write_b64. c-state in registers. Bias+x via augmented K=288
// ("1" column). Decoder feedback folded into weights (R3 trick) -> 1
// barrier/step everywhere, out-projection off the critical path.

#define SEQ  20
#define TLEN 30

typedef _Float16 half8   __attribute__((ext_vector_type(8)));
typedef _Float16 half4   __attribute__((ext_vector_type(4)));
typedef float    floatx4 __attribute__((ext_vector_type(4)));

// Packed weights, rewritten every launch. For gate row n (0..1023), k (0..287):
//   t=n>>4, l16=n&15, g=t>>4, w=(t>>2)&3, cc=t&3, i=cc*4+g,
//   kt=k>>5, q=(k>>3)&3, j=k&7
//   dst = ((w*9+kt)*16 + i)*512 + q*128 + l16*8 + j
// => per (wave,kt): 16 contiguous 1KB fragments (16KB block).
__device__ _Float16 g_w_enc[1024 * 288];   // x-cols: W_ih_enc@W_emb; "1": b_enc+W_ih_enc@b_emb
__device__ _Float16 g_w_dec0[1024 * 288];  // x-cols: W_ih_dec;        "1": b_dec
__device__ _Float16 g_w_deff[1024 * 288];  // W_hh_dec+W_ih_dec@W_out; "1": b_eff
__device__ _Float16 g_wout[512];           // W_out [2][256] f16

__global__ void prep_kernel(const float* __restrict__ W_emb,
                            const float* __restrict__ b_emb,
                            const float* __restrict__ W_ih_enc,
                            const float* __restrict__ W_hh_enc,
                            const float* __restrict__ b_enc,
                            const float* __restrict__ W_ih_dec,
                            const float* __restrict__ W_hh_dec,
                            const float* __restrict__ b_dec,
                            const float* __restrict__ W_out,
                            const float* __restrict__ b_out) {
    int gid = blockIdx.x * blockDim.x + threadIdx.x;
    int stride = gridDim.x * blockDim.x;
    for (int s = gid; s < 1024 * 288; s += stride) {
        int n = s / 288, k = s - n * 288;
        int t = n >> 4, l16 = n & 15;
        int g = t >> 4, w = (t >> 2) & 3, cc = t & 3;
        int i = cc * 4 + g;
        int kt = k >> 5, q = (k >> 3) & 3, j = k & 7;
        int dst = ((w * 9 + kt) * 16 + i) * 512 + q * 128 + l16 * 8 + j;
        float fe = 0.f, fd = 0.f, ff = 0.f;
        if (k < 256) {
            fe = W_hh_enc[n * 256 + k];
            fd = W_hh_dec[n * 256 + k];
            ff = fd + W_ih_dec[2 * n] * W_out[k]
                    + W_ih_dec[2 * n + 1] * W_out[256 + k];
        } else {
            int kp = k - 256;
            if (kp < 2) {
                fd = W_ih_dec[2 * n + kp];
                const float* wr = &W_ih_enc[n * 64];
                for (int e = 0; e < 64; e++) fe = fmaf(wr[e], W_emb[2 * e + kp], fe);
            } else if (kp == 2) {
                fd = b_dec[n];
                ff = b_dec[n] + W_ih_dec[2 * n] * b_out[0]
                              + W_ih_dec[2 * n + 1] * b_out[1];
                fe = b_enc[n];
                const float* wr = &W_ih_enc[n * 64];
                for (int e = 0; e < 64; e++) fe = fmaf(wr[e], b_emb[e], fe);
            }
        }
        g_w_enc[dst]  = (_Float16)fe;
        g_w_dec0[dst] = (_Float16)fd;
        g_w_deff[dst] = (_Float16)ff;
    }
    if (gid < 512) g_wout[gid] = (_Float16)W_out[gid];
}

__global__ __launch_bounds__(256, 2) void lstm_fused(
        const float* __restrict__ x_input,    // [20][16384][2]
        const float* __restrict__ b_out,      // [2]
        float* __restrict__ out)              // [30][16384][2]
{
    // h as B-operand: [buf][nt(2)][kt(9)][512] halves; batch=16nt+l16,
    // k = 32kt+8q+j. kt=8 slots j=0,1 hold x; j=2 holds the "1".
    __shared__ __align__(16) _Float16 h_pack[2][9216];   // 36864 B
    __shared__ __align__(16) _Float16 wout_lds[512];     // 1024 B

    const int tid = threadIdx.x;
    const int w   = tid >> 6;       // wave 0..3, owns hidden cols [64w,64w+64)
    const int L   = tid & 63;
    const int l16 = L & 15;
    const int q   = L >> 4;
    const long row0 = (long)blockIdx.x * 32;

    // ---- init ----
    {
        int* hz = (int*)&h_pack[0][0];
        for (int idx = tid; idx < 9216; idx += 256) hz[idx] = 0;  // both bufs
        wout_lds[tid]       = g_wout[tid];
        wout_lds[tid + 256] = g_wout[tid + 256];
    }
    __syncthreads();
    if (tid < 64) {   // "1" column, both buffers, never overwritten
        int buf = tid >> 5, b = tid & 31;
        h_pack[buf][((b >> 4) * 9 + 8) * 512 + (b & 15) * 8 + 2] = (_Float16)1.f;
    }
    if (tid < 64) {   // x(0) into buf0
        int b = tid >> 1, jj = tid & 1;
        h_pack[0][((b >> 4) * 9 + 8) * 512 + (b & 15) * 8 + jj] =
            (_Float16)x_input[(row0 + b) * 2 + jj];
    }

    const float bo = b_out[(tid >> 2) & 1];
    const int aoff  = q * 128 + l16 * 8;
    const int wbase = w * 73728;    // w*9*16*512

    floatx4 acc[16][2];   // [i][nt]; D: row=gate 16t(i)+4q+r, col=batch 16nt+l16
    float   c_st[2][16];  // [nt][cc*4+r]
#pragma unroll
    for (int nt = 0; nt < 2; nt++)
#pragma unroll
        for (int z = 0; z < 16; z++) c_st[nt][z] = 0.f;

    __syncthreads();

    int cur = 0;
#pragma unroll 1
    for (int t = 0; t < SEQ + TLEN; t++) {
        const _Float16* __restrict__ Wb =
            (t < SEQ) ? g_w_enc : (t == SEQ) ? g_w_dec0 : g_w_deff;
        const _Float16* __restrict__ hp = h_pack[cur];
        _Float16* __restrict__ hn = h_pack[cur ^ 1];

#pragma unroll
        for (int i = 0; i < 16; i++) {
            acc[i][0] = (floatx4)(0.f);
            acc[i][1] = (floatx4)(0.f);
        }

        // ---- gates = [h|x|1] @ Waug^T : A=weights(L2), B=h(LDS) ----
#pragma unroll
        for (int kt = 0; kt < 9; kt++) {
            half8 B0 = *(const half8*)&hp[kt * 512 + aoff];
            half8 B1 = *(const half8*)&hp[(9 + kt) * 512 + aoff];
#pragma unroll
            for (int i = 0; i < 16; i++) {
                half8 Aw = *(const half8*)&Wb[wbase + (kt * 16 + i) * 512 + aoff];
                acc[i][0] = __builtin_amdgcn_mfma_f32_16x16x32_f16(Aw, B0, acc[i][0], 0, 0, 0);
                acc[i][1] = __builtin_amdgcn_mfma_f32_16x16x32_f16(Aw, B1, acc[i][1], 0, 0, 0);
            }
        }

        // next-step x load (encoder; t==19 re-feeds x19 for dec step 0)
        float xval = 0.f;
        if (t < SEQ && tid < 64) {
            int srct = (t + 1 < SEQ) ? t + 1 : SEQ - 1;
            xval = x_input[(long)srct * 32768 + (row0 + (tid >> 1)) * 2 + (tid & 1)];
        }

        // ---- elementwise LSTM; packed b64 h-writes into hn ----
#pragma unroll
        for (int nt = 0; nt < 2; nt++)
#pragma unroll
            for (int cc = 0; cc < 4; cc++) {
                half4 hv4;
#pragma unroll
                for (int r = 0; r < 4; r++) {
                    float ai = acc[cc * 4 + 0][nt][r];
                    float af = acc[cc * 4 + 1][nt][r];
                    float ag = fmaxf(acc[cc * 4 + 2][nt][r], -30.f);
                    float ao = acc[cc * 4 + 3][nt][r];
                    float eI = __expf(-ai);
                    float eG = __expf(-2.f * ag);
                    float eF = __expf(-af);
                    float ig = (1.f - eG) *
                        __builtin_amdgcn_rcpf((1.f + eI) * (1.f + eG));
                    float fs = __builtin_amdgcn_rcpf(1.f + eF);
                    float cn = fmaf(fs, c_st[nt][cc * 4 + r], ig);
                    c_st[nt][cc * 4 + r] = cn;
                    float cnc = fmaxf(cn, -30.f);
                    float eO = __expf(-ao);
                    float eC = __expf(-2.f * cnc);
                    hv4[r] = (_Float16)((1.f - eC) *
                        __builtin_amdgcn_rcpf((1.f + eO) * (1.f + eC)));
                }
                // col0 = 64w + 16cc + 4q ; 4 consecutive halves (r=0..3)
                int kt2 = 2 * w + (cc >> 1);
                int q2  = 2 * (cc & 1) + (q >> 1);
                int j0  = 4 * (q & 1);
                *(half4*)&hn[(nt * 9 + kt2) * 512 + q2 * 128 + l16 * 8 + j0] = hv4;
            }

        if (t < SEQ && tid < 64) {
            int b = tid >> 1, jj = tid & 1;
            hn[((b >> 4) * 9 + 8) * 512 + (b & 15) * 8 + jj] = (_Float16)xval;
        }

        __syncthreads();   // hn complete

        // ---- out = h_new @ W_out^T + b_out (feedback folded; reads only) ----
        if (t >= SEQ) {
            int o = tid >> 2;              // 0..63
            int m = o >> 1, jj = o & 1, sub = tid & 3;
            float s = 0.f;
#pragma unroll
            for (int p = 0; p < 8; p++) {
                int col = 64 * sub + 8 * p;
                half8 hv = *(const half8*)&hn[((m >> 4) * 9 + (col >> 5)) * 512 +
                                              ((col >> 3) & 3) * 128 + (m & 15) * 8];
                half8 wv = *(const half8*)&wout_lds[jj * 256 + col];
#pragma unroll
                for (int u = 0; u < 8; u++)
                    s = fmaf((float)hv[u], (float)wv[u], s);
            }
            s += __shfl_xor(s, 1);
            s += __shfl_xor(s, 2);
            if (sub == 0)
                out[(long)(t - SEQ) * 32768 + (row0 + m) * 2 + jj] = s + bo;
        }

        cur ^= 1;
    }
}

extern "C" void kernel_launch(void* const* d_in, const int* in_sizes, int n_in,
                              void* d_out, int out_size, void* d_ws, size_t ws_size,
                              hipStream_t stream) {
    (void)in_sizes; (void)n_in; (void)d_ws; (void)ws_size; (void)out_size;
    const float* x      = (const float*)d_in[0];
    const float* W_emb  = (const float*)d_in[1];
    const float* b_emb  = (const float*)d_in[2];
    const float* W_ih_e = (const float*)d_in[3];
    const float* W_hh_e = (const float*)d_in[4];
    const float* b_enc  = (const float*)d_in[5];
    const float* W_ih_d = (const float*)d_in[6];
    const float* W_hh_d = (const float*)d_in[7];
    const float* b_dec  = (const float*)d_in[8];
    const float* W_out  = (const float*)d_in[9];
    const float* b_out  = (const float*)d_in[10];
    float* outp = (float*)d_out;

    prep_kernel<<<512, 256, 0, stream>>>(W_emb, b_emb, W_ih_e, W_hh_e, b_enc,
                                         W_ih_d, W_hh_d, b_dec, W_out, b_out);
    lstm_fused<<<512, 256, 0, stream>>>(x, b_out, outp);
}

// Round 5
// 660.264 us; speedup vs baseline: 2.4654x; 1.1176x over previous
//
#include <hip/hip_runtime.h>

// lstm_seq2seq fused persistent kernel for MI355X (gfx950), R5.
// 256 WGs x 512 threads x 64 rows (1 WG/CU): each CU streams the 576 KB
// augmented gate matrix from L2 exactly ONCE per step (R4's 2 WG/CU doubled
// this and was L2-bound at ~740 us). 8 waves, each owning 8 gate-tiles
// (cells [64w,64w+32) x 4 gates) x 4 batch-tiles. A=weights (L2, wave-
// contiguous packing), B=h (LDS, double-buffered). c-state + out-projection
// partials in registers; decoder feedback folded into weights (verified
// R3/R4); K=288 augmented ("1" column carries bias, x in kt=8).
// launch_bounds(512,2): 256 unified regs = acc 128 AGPR + ~115 VGPR.

#define SEQ  20
#define TLEN 30

typedef _Float16 half8   __attribute__((ext_vector_type(8)));
typedef _Float16 half4   __attribute__((ext_vector_type(4)));
typedef float    floatx4 __attribute__((ext_vector_type(4)));

// Packed weights. Gate row n (0..1023), k (0..287):
//   g=n>>8, c=(n>>4)&15, l16=n&15, w=c>>1, cc=c&1, i=cc*4+g,
//   kt=k>>5, q=(k>>3)&3, j=k&7
//   dst = ((w*9+kt)*8 + i)*512 + q*128 + l16*8 + j
// => per (wave,kt): 8 contiguous 1KB A-fragments (8KB block).
__device__ _Float16 g_w_enc[1024 * 288];   // x-cols: W_ih_enc@W_emb; "1": b_enc+W_ih_enc@b_emb
__device__ _Float16 g_w_dec0[1024 * 288];  // x-cols: W_ih_dec;        "1": b_dec
__device__ _Float16 g_w_deff[1024 * 288];  // W_hh_dec+W_ih_dec@W_out; "1": b_eff
__device__ _Float16 g_wout[512];           // W_out [2][256] f16

__global__ void prep_kernel(const float* __restrict__ W_emb,
                            const float* __restrict__ b_emb,
                            const float* __restrict__ W_ih_enc,
                            const float* __restrict__ W_hh_enc,
                            const float* __restrict__ b_enc,
                            const float* __restrict__ W_ih_dec,
                            const float* __restrict__ W_hh_dec,
                            const float* __restrict__ b_dec,
                            const float* __restrict__ W_out,
                            const float* __restrict__ b_out) {
    int gid = blockIdx.x * blockDim.x + threadIdx.x;
    int stride = gridDim.x * blockDim.x;
    for (int s = gid; s < 1024 * 288; s += stride) {
        int n = s / 288, k = s - n * 288;
        int g = n >> 8, c = (n >> 4) & 15, l16 = n & 15;
        int w = c >> 1, cc = c & 1;
        int i = cc * 4 + g;
        int kt = k >> 5, q = (k >> 3) & 3, j = k & 7;
        int dst = ((w * 9 + kt) * 8 + i) * 512 + q * 128 + l16 * 8 + j;
        float fe = 0.f, fd = 0.f, ff = 0.f;
        if (k < 256) {
            fe = W_hh_enc[n * 256 + k];
            fd = W_hh_dec[n * 256 + k];
            ff = fd + W_ih_dec[2 * n] * W_out[k]
                    + W_ih_dec[2 * n + 1] * W_out[256 + k];
        } else {
            int kp = k - 256;
            if (kp < 2) {
                fd = W_ih_dec[2 * n + kp];
                const float* wr = &W_ih_enc[n * 64];
                for (int e = 0; e < 64; e++) fe = fmaf(wr[e], W_emb[2 * e + kp], fe);
            } else if (kp == 2) {
                fd = b_dec[n];
                ff = b_dec[n] + W_ih_dec[2 * n] * b_out[0]
                              + W_ih_dec[2 * n + 1] * b_out[1];
                fe = b_enc[n];
                const float* wr = &W_ih_enc[n * 64];
                for (int e = 0; e < 64; e++) fe = fmaf(wr[e], b_emb[e], fe);
            }
        }
        g_w_enc[dst]  = (_Float16)fe;
        g_w_dec0[dst] = (_Float16)fd;
        g_w_deff[dst] = (_Float16)ff;
    }
    if (gid < 512) g_wout[gid] = (_Float16)W_out[gid];
}

__global__ __launch_bounds__(512, 2) void lstm_fused(
        const float* __restrict__ x_input,    // [20][16384][2]
        const float* __restrict__ b_out,      // [2]
        float* __restrict__ out)              // [30][16384][2]
{
    // h as B-operand: [buf][nt(4)][kt(9)][512] halves; batch=16nt+l16,
    // k = 32kt+8q+j. kt=8: j=0,1 hold x; j=2 holds the "1" (bias column).
    __shared__ __align__(16) _Float16 h_pack[2][18432];        // 73728 B
    __shared__ __align__(16) float    partial_lds[2][8 * 132]; // 8448 B

    const int tid = threadIdx.x;
    const int w   = tid >> 6;       // wave 0..7, owns cells [32w, 32w+32)
    const int L   = tid & 63;
    const int l16 = L & 15;
    const int q   = L >> 4;
    const long row0 = (long)blockIdx.x * 64;

    // ---- init ----
    {
        int* hz = (int*)&h_pack[0][0];
        for (int idx = tid; idx < 18432; idx += 512) hz[idx] = 0;  // both bufs
    }
    __syncthreads();
    if (tid < 128) {   // "1" column, both buffers, never overwritten
        int buf = tid >> 6, b = tid & 63;
        h_pack[buf][((b >> 4) * 9 + 8) * 512 + (b & 15) * 8 + 2] = (_Float16)1.f;
    }
    if (tid < 128) {   // x(0) into buf0
        int b = tid >> 1, jj = tid & 1;
        h_pack[0][((b >> 4) * 9 + 8) * 512 + (b & 15) * 8 + jj] =
            (_Float16)x_input[(row0 + b) * 2 + jj];
    }

    const float bo = b_out[tid & 1];
    const int aoff = q * 128 + l16 * 8;
    const _Float16* __restrict__ wenc_w  = &g_w_enc[w * 36864];
    const _Float16* __restrict__ wdec0_w = &g_w_dec0[w * 36864];
    const _Float16* __restrict__ wdeff_w = &g_w_deff[w * 36864];

    // W_out values for this lane's 8 cells: cell = 32w + 16cc + 4q + r
    _Float16 wo[2][2][4];   // [jj][cc][r]
#pragma unroll
    for (int jj = 0; jj < 2; jj++)
#pragma unroll
        for (int cc = 0; cc < 2; cc++)
#pragma unroll
            for (int r = 0; r < 4; r++)
                wo[jj][cc][r] = g_wout[jj * 256 + 32 * w + 16 * cc + 4 * q + r];

    floatx4 acc[8][4];     // [i=cc*4+g][nt]; D: row(gate l4)=4q+r, col(batch)=l16
    float   c_st[4][2][4]; // [nt][cc][r]
#pragma unroll
    for (int nt = 0; nt < 4; nt++)
#pragma unroll
        for (int cc = 0; cc < 2; cc++)
#pragma unroll
            for (int r = 0; r < 4; r++) c_st[nt][cc][r] = 0.f;

    __syncthreads();

    int cur = 0;
#pragma unroll 1
    for (int t = 0; t < SEQ + TLEN; t++) {
        const _Float16* __restrict__ Wb =
            (t < SEQ) ? wenc_w : (t == SEQ) ? wdec0_w : wdeff_w;
        const _Float16* __restrict__ hp = h_pack[cur];
        _Float16* __restrict__ hn = h_pack[cur ^ 1];

#pragma unroll
        for (int i = 0; i < 8; i++)
#pragma unroll
            for (int nt = 0; nt < 4; nt++) acc[i][nt] = (floatx4)(0.f);

        // ---- gates = [h|x|1] @ Waug^T : A=weights(L2), B=h(LDS) ----
#pragma unroll
        for (int kt = 0; kt < 9; kt++) {
            half8 B[4];
#pragma unroll
            for (int nt = 0; nt < 4; nt++)
                B[nt] = *(const half8*)&hp[(nt * 9 + kt) * 512 + aoff];
#pragma unroll
            for (int i = 0; i < 8; i++) {
                half8 Aw = *(const half8*)&Wb[(kt * 8 + i) * 512 + aoff];
#pragma unroll
                for (int nt = 0; nt < 4; nt++)
                    acc[i][nt] = __builtin_amdgcn_mfma_f32_16x16x32_f16(
                        Aw, B[nt], acc[i][nt], 0, 0, 0);
            }
        }

        // next-step x load (encoder; t==19 re-feeds x19 for dec step 0)
        float xval = 0.f;
        if (t < SEQ && tid < 128) {
            int srct = (t + 1 < SEQ) ? t + 1 : SEQ - 1;
            xval = x_input[(long)srct * 32768 + (row0 + (tid >> 1)) * 2 + (tid & 1)];
        }

        // ---- elementwise LSTM; packed b64 h-writes; out-proj partials ----
        const bool dec = (t >= SEQ);
        float po[4][2];   // [nt][jj]
#pragma unroll
        for (int nt = 0; nt < 4; nt++) { po[nt][0] = 0.f; po[nt][1] = 0.f; }

#pragma unroll
        for (int nt = 0; nt < 4; nt++)
#pragma unroll
            for (int cc = 0; cc < 2; cc++) {
                half4 hv4;
                float hvf[4];
#pragma unroll
                for (int r = 0; r < 4; r++) {
                    float ai = acc[cc * 4 + 0][nt][r];
                    float af = acc[cc * 4 + 1][nt][r];
                    float ag = fmaxf(acc[cc * 4 + 2][nt][r], -30.f);
                    float ao = acc[cc * 4 + 3][nt][r];
                    float eI = __expf(-ai);
                    float eG = __expf(-2.f * ag);
                    float eF = __expf(-af);
                    float ig = (1.f - eG) *
                        __builtin_amdgcn_rcpf((1.f + eI) * (1.f + eG));
                    float fs = __builtin_amdgcn_rcpf(1.f + eF);
                    float cn = fmaf(fs, c_st[nt][cc][r], ig);
                    c_st[nt][cc][r] = cn;
                    float cnc = fmaxf(cn, -30.f);
                    float eO = __expf(-ao);
                    float eC = __expf(-2.f * cnc);
                    float hv = (1.f - eC) *
                        __builtin_amdgcn_rcpf((1.f + eO) * (1.f + eC));
                    hvf[r] = hv;
                    hv4[r] = (_Float16)hv;
                }
                // cell = 32w+16cc+4q+r -> kt2=w, q2=2cc+(q>>1), j0=4(q&1)
                *(half4*)&hn[(nt * 9 + w) * 512 + (2 * cc + (q >> 1)) * 128 +
                             l16 * 8 + 4 * (q & 1)] = hv4;
                if (dec) {
#pragma unroll
                    for (int r = 0; r < 4; r++) {
                        po[nt][0] = fmaf(hvf[r], (float)wo[0][cc][r], po[nt][0]);
                        po[nt][1] = fmaf(hvf[r], (float)wo[1][cc][r], po[nt][1]);
                    }
                }
            }

        if (dec) {
            // reduce over q (cells 4q+r live in different lanes, same batch)
#pragma unroll
            for (int nt = 0; nt < 4; nt++)
#pragma unroll
                for (int jj = 0; jj < 2; jj++) {
                    float s = po[nt][jj];
                    s += __shfl_xor(s, 16);
                    s += __shfl_xor(s, 32);
                    po[nt][jj] = s;
                }
            if (q == 0) {
                float* pl = &partial_lds[t & 1][w * 132];
#pragma unroll
                for (int nt = 0; nt < 4; nt++) {
                    pl[nt * 16 + l16]      = po[nt][0];
                    pl[66 + nt * 16 + l16] = po[nt][1];
                }
            }
        }

        if (t < SEQ && tid < 128) {
            int b = tid >> 1, jj = tid & 1;
            hn[((b >> 4) * 9 + 8) * 512 + (b & 15) * 8 + jj] = (_Float16)xval;
        }

        __syncthreads();   // hn + partials complete

        if (dec && tid < 128) {
            int m = tid >> 1, jj = tid & 1;
            const float* pl = &partial_lds[t & 1][jj * 66 + m];
            float s = bo;
#pragma unroll
            for (int w8 = 0; w8 < 8; w8++) s += pl[w8 * 132];
            out[(long)(t - SEQ) * 32768 + (row0 + m) * 2 + jj] = s;
        }

        cur ^= 1;
    }
}

extern "C" void kernel_launch(void* const* d_in, const int* in_sizes, int n_in,
                              void* d_out, int out_size, void* d_ws, size_t ws_size,
                              hipStream_t stream) {
    (void)in_sizes; (void)n_in; (void)d_ws; (void)ws_size; (void)out_size;
    const float* x      = (const float*)d_in[0];
    const float* W_emb  = (const float*)d_in[1];
    const float* b_emb  = (const float*)d_in[2];
    const float* W_ih_e = (const float*)d_in[3];
    const float* W_hh_e = (const float*)d_in[4];
    const float* b_enc  = (const float*)d_in[5];
    const float* W_ih_d = (const float*)d_in[6];
    const float* W_hh_d = (const float*)d_in[7];
    const float* b_dec  = (const float*)d_in[8];
    const float* W_out  = (const float*)d_in[9];
    const float* b_out  = (const float*)d_in[10];
    float* outp = (float*)d_out;

    prep_kernel<<<512, 256, 0, stream>>>(W_emb, b_emb, W_ih_e, W_hh_e, b_enc,
                                         W_ih_d, W_hh_d, b_dec, W_out, b_out);
    lstm_fused<<<256, 512, 0, stream>>>(x, b_out, outp);
}